// Round 7
// baseline (168.981 us; speedup 1.0000x reference)
//
#include <hip/hip_runtime.h>
#include <math.h>

#define P 4096
#define NB 2
#define NROWS (NB * P)                // 8192
#define THREADS 512
#define NWAVE (THREADS / 64)          // 8
#define R 8                           // rows per block
#define NCHUNK (P / THREADS)          // 8 columns per thread
#define NBLK (NROWS / R)              // 1024 blocks per orientation
#define SQRT_LOG2E 1.2011224087864498f
// base-2 domain: pot2 = pot * log2(e); log2(1/4096) = -12 exactly.
#define LOG2_INV_P (-12.0f)
// frozen iff err_nat_sum < 0.02  <=>  sum|d_u2| < 0.02/ln2
#define ERR_T2 0.028853900817779268f
#define C_DIST 1.6922538540598323e-4f    // ln(2)/4096

// ws float layout:
//   [0..8192)      u2      (base-2 row potential)
//   [8192..16384)  v2      (zero-inited by prep: used if frozen at i=0)
//   [16384..16388) err0..2 + pad
//   [16640 + a*8192), a=0..7: SoA xs0,xs1,xs2,xn, ys0,ys1,ys2,yn
//     xs = x*s, xn = |xs|^2 ; ys = 2*s*y, yn = |s*y|^2  (s = sqrt(log2e))
//     => m2 = w2 - xn - yn + <xs,ys> = log2e * (w - |x-y|^2)
#define WS_U   0
#define WS_V   NROWS
#define WS_ERR (2 * NROWS)
#define WS_SOA 16640

// d_out layout (floats): [0]=distance, [1..8192]=corr1, [8193..16384]=corr2

// NOTE: __launch_bounds__(THREADS, 4) in R4-R6 clamped VGPR to 64 and forced
// ~40 MB/dispatch of scratch spill (rocprof: VGPR_Count=64, WRITE_SIZE 30 MB).
// Plain __launch_bounds__(THREADS) lets the register-resident inner loop
// actually live in registers (~110 VGPR, 4 waves/SIMD is still fine).

__device__ __forceinline__ float exp2_hw(float x) {
    float r;
    asm("v_exp_f32 %0, %1" : "=v"(r) : "v"(x));   // 2^x, single instr
    return r;
}

__global__ void prep_kernel(const float* __restrict__ x, const float* __restrict__ y,
                            float* __restrict__ ws, float* __restrict__ out) {
    const int idx = blockIdx.x * blockDim.x + threadIdx.x;  // 0..16383
    float* __restrict__ soa = ws + WS_SOA;
    if (idx < NROWS) {
        const float a0 = x[idx * 3 + 0] * SQRT_LOG2E;
        const float a1 = x[idx * 3 + 1] * SQRT_LOG2E;
        const float a2 = x[idx * 3 + 2] * SQRT_LOG2E;
        soa[0 * NROWS + idx] = a0;
        soa[1 * NROWS + idx] = a1;
        soa[2 * NROWS + idx] = a2;
        soa[3 * NROWS + idx] = a0 * a0 + a1 * a1 + a2 * a2;
        ws[WS_V + idx] = 0.0f;
    } else {
        const int k = idx - NROWS;
        const float a0 = y[k * 3 + 0] * SQRT_LOG2E;
        const float a1 = y[k * 3 + 1] * SQRT_LOG2E;
        const float a2 = y[k * 3 + 2] * SQRT_LOG2E;
        soa[4 * NROWS + k] = a0 + a0;   // 2*s*y for the fma dot (factor 2 baked in)
        soa[5 * NROWS + k] = a1 + a1;
        soa[6 * NROWS + k] = a2 + a2;
        soa[7 * NROWS + k] = a0 * a0 + a1 * a1 + a2 * a2;  // s^2|y|^2
    }
    if (idx < 4) ws[WS_ERR + idx] = 0.0f;
    if (idx == 4) out[0] = 0.0f;        // distance accumulator (d_out is poisoned)
}

// pot2[row] = -12 - log2( sum_j exp2( w2_j - cn_j - rn_r + <rc_r, cc_j> ) )
// All of the thread's column strip (coords + a_k = w2-cn) is loaded into
// registers up-front -> inner 64 iterations are pure VALU (no memory stalls).
// ZERO_W: w2==0 and old-pot==0 (iteration-0 state). Sticky freeze via chk*.
template <int WITH_ERR, int ZERO_W>
__global__ __launch_bounds__(THREADS) void lse_single(
    const float* __restrict__ rc0, const float* __restrict__ rc1,
    const float* __restrict__ rc2, const float* __restrict__ rn,   // row-side SoA
    const float* __restrict__ cc0, const float* __restrict__ cc1,
    const float* __restrict__ cc2, const float* __restrict__ cn,   // col-side SoA
    const float* __restrict__ w2,     // other potential (base-2)
    float* __restrict__ pot2,         // potential to update (base-2)
    float* __restrict__ err_acc,
    const float* __restrict__ chk0, const float* __restrict__ chk1)
{
    bool frozen = false;
    if (chk0) frozen = frozen || (*chk0 < ERR_T2);
    if (chk1) frozen = frozen || (*chk1 < ERR_T2);
    if (frozen) return;  // uniform across grid

    __shared__ float red[NWAVE * R];

    const int row0 = blockIdx.x * R;
    const int bofs = (row0 >> 12) << 12;
    const int t = threadIdx.x;
    const int wid = t >> 6, lane = t & 63;
    const int jbase = bofs + t;

    float r0[R], r1[R], r2[R], rnm[R];
#pragma unroll
    for (int r = 0; r < R; r++) {
        r0[r] = rc0[row0 + r];
        r1[r] = rc1[row0 + r];
        r2[r] = rc2[row0 + r];
        rnm[r] = rn[row0 + r];
    }
    float c0[NCHUNK], c1[NCHUNK], c2[NCHUNK], a[NCHUNK];
#pragma unroll
    for (int k = 0; k < NCHUNK; k++) {
        const int j = jbase + k * THREADS;
        c0[k] = cc0[j];
        c1[k] = cc1[j];
        c2[k] = cc2[j];
        a[k] = (ZERO_W ? 0.0f : w2[j]) - cn[j];
    }

    float s[R];
#pragma unroll
    for (int r = 0; r < R; r++) s[r] = 0.0f;

#pragma unroll
    for (int k = 0; k < NCHUNK; k++) {
#pragma unroll
        for (int r = 0; r < R; r++) {
            const float b = a[k] - rnm[r];
            const float m2 = fmaf(c0[k], r0[r], fmaf(c1[k], r1[r], fmaf(c2[k], r2[r], b)));
            s[r] += exp2_hw(m2);
        }
    }
#pragma unroll
    for (int r = 0; r < R; r++) {
        float v2 = s[r];
#pragma unroll
        for (int off = 32; off >= 1; off >>= 1)
            v2 += __shfl_down(v2, off, 64);
        if (lane == 0) red[wid * R + r] = v2;
    }
    __syncthreads();
    if (t < R) {
        float ssum = red[t];
#pragma unroll
        for (int w = 1; w < NWAVE; w++) ssum += red[w * R + t];
        const float pn = LOG2_INV_P - __log2f(ssum);
        float d = 0.0f;
        if (WITH_ERR) d = fabsf(pn - (ZERO_W ? 0.0f : pot2[row0 + t]));
        pot2[row0 + t] = pn;
        if (WITH_ERR) {
#pragma unroll
            for (int off = R / 2; off >= 1; off >>= 1)
                d += __shfl_down(d, off, R);
            if (t == 0) atomicAdd(err_acc, d);
        }
    }
}

// Fused lse#5 + corr1 + distance (u_final == f(v_final) in all freeze cases):
//   S_i = sum_j e_ij,  D2_i = sum_j e_ij*(v2_j - m2_ij)   [= log2e * C]
//   u2_i = -12 - log2(S_i);  dist_i = (ln2/P) * D2_i / S_i
//   corr1_i = argmax_j m2_ij (first-index ties; monotone in reference pi)
__global__ __launch_bounds__(THREADS) void row_final(
    const float* __restrict__ rc0, const float* __restrict__ rc1,
    const float* __restrict__ rc2, const float* __restrict__ rn,   // x SoA
    const float* __restrict__ cc0, const float* __restrict__ cc1,
    const float* __restrict__ cc2, const float* __restrict__ cn,   // y SoA
    const float* __restrict__ w2,     // final v2
    float* __restrict__ u2_out,
    float* __restrict__ corr1,
    float* __restrict__ dist)
{
    __shared__ float redS[NWAVE * R];
    __shared__ float redD[NWAVE * R];
    __shared__ float redv[NWAVE * R];
    __shared__ int   redj[NWAVE * R];

    const int row0 = blockIdx.x * R;
    const int bofs = (row0 >> 12) << 12;
    const int t = threadIdx.x;
    const int wid = t >> 6, lane = t & 63;
    const int jbase = bofs + t;

    float r0[R], r1[R], r2[R], rnm[R];
#pragma unroll
    for (int r = 0; r < R; r++) {
        r0[r] = rc0[row0 + r];
        r1[r] = rc1[row0 + r];
        r2[r] = rc2[row0 + r];
        rnm[r] = rn[row0 + r];
    }
    float c0[NCHUNK], c1[NCHUNK], c2[NCHUNK], a[NCHUNK], wv[NCHUNK];
#pragma unroll
    for (int k = 0; k < NCHUNK; k++) {
        const int j = jbase + k * THREADS;
        c0[k] = cc0[j];
        c1[k] = cc1[j];
        c2[k] = cc2[j];
        wv[k] = w2[j];
        a[k] = wv[k] - cn[j];
    }

    float S[R], D[R], bv[R];
    int bj[R];
#pragma unroll
    for (int r = 0; r < R; r++) { S[r] = 0.0f; D[r] = 0.0f; bv[r] = -INFINITY; bj[r] = 0; }

#pragma unroll
    for (int k = 0; k < NCHUNK; k++) {
#pragma unroll
        for (int r = 0; r < R; r++) {
            const float b = a[k] - rnm[r];
            const float m2 = fmaf(c0[k], r0[r], fmaf(c1[k], r1[r], fmaf(c2[k], r2[r], b)));
            const float e = exp2_hw(m2);
            S[r] += e;
            D[r] = fmaf(e, wv[k] - m2, D[r]);     // (v2 - m2) = log2e * C >= 0
            const bool pgt = m2 > bv[r];          // strict >, k ascending -> first max
            bj[r] = pgt ? (t + k * THREADS) : bj[r];
            bv[r] = pgt ? m2 : bv[r];
        }
    }
#pragma unroll
    for (int r = 0; r < R; r++) {
        float sS = S[r], sD = D[r], v2 = bv[r];
        int j2 = bj[r];
#pragma unroll
        for (int off = 32; off >= 1; off >>= 1) {
            sS += __shfl_down(sS, off, 64);
            sD += __shfl_down(sD, off, 64);
            const float ov = __shfl_down(v2, off, 64);
            const int   oj = __shfl_down(j2, off, 64);
            const bool take = (ov > v2) || (ov == v2 && oj < j2);
            v2 = take ? ov : v2;
            j2 = take ? oj : j2;
        }
        if (lane == 0) {
            redS[wid * R + r] = sS;
            redD[wid * R + r] = sD;
            redv[wid * R + r] = v2;
            redj[wid * R + r] = j2;
        }
    }
    __syncthreads();
    if (t < R) {
        float sS = redS[t], sD = redD[t], v2 = redv[t];
        int j2 = redj[t];
#pragma unroll
        for (int w = 1; w < NWAVE; w++) {
            sS += redS[w * R + t];
            sD += redD[w * R + t];
            const float ov = redv[w * R + t];
            const int   oj = redj[w * R + t];
            const bool take = (ov > v2) || (ov == v2 && oj < j2);
            v2 = take ? ov : v2;
            j2 = take ? oj : j2;
        }
        u2_out[row0 + t] = LOG2_INV_P - __log2f(sS);
        corr1[row0 + t] = (float)j2;
        float dp = C_DIST * sD / sS;
#pragma unroll
        for (int off = R / 2; off >= 1; off >>= 1)
            dp += __shfl_down(dp, off, R);
        if (t == 0) atomicAdd(dist, dp);
    }
}

// corr2_j = argmax_i m2_ij : rows = y points, cols = x points (+ final u2).
__global__ __launch_bounds__(THREADS) void col_final(
    const float* __restrict__ rc0, const float* __restrict__ rc1,
    const float* __restrict__ rc2, const float* __restrict__ rn,   // y SoA
    const float* __restrict__ cc0, const float* __restrict__ cc1,
    const float* __restrict__ cc2, const float* __restrict__ cn,   // x SoA
    const float* __restrict__ w2,     // final u2
    float* __restrict__ corr2)
{
    __shared__ float redv[NWAVE * R];
    __shared__ int   redj[NWAVE * R];

    const int row0 = blockIdx.x * R;
    const int bofs = (row0 >> 12) << 12;
    const int t = threadIdx.x;
    const int wid = t >> 6, lane = t & 63;
    const int jbase = bofs + t;

    float r0[R], r1[R], r2[R], rnm[R];
#pragma unroll
    for (int r = 0; r < R; r++) {
        r0[r] = rc0[row0 + r];
        r1[r] = rc1[row0 + r];
        r2[r] = rc2[row0 + r];
        rnm[r] = rn[row0 + r];
    }
    float c0[NCHUNK], c1[NCHUNK], c2[NCHUNK], a[NCHUNK];
#pragma unroll
    for (int k = 0; k < NCHUNK; k++) {
        const int j = jbase + k * THREADS;
        c0[k] = cc0[j];
        c1[k] = cc1[j];
        c2[k] = cc2[j];
        a[k] = w2[j] - cn[j];
    }

    float bv[R];
    int bj[R];
#pragma unroll
    for (int r = 0; r < R; r++) { bv[r] = -INFINITY; bj[r] = 0; }

#pragma unroll
    for (int k = 0; k < NCHUNK; k++) {
#pragma unroll
        for (int r = 0; r < R; r++) {
            const float b = a[k] - rnm[r];
            const float m2 = fmaf(c0[k], r0[r], fmaf(c1[k], r1[r], fmaf(c2[k], r2[r], b)));
            const bool pgt = m2 > bv[r];
            bj[r] = pgt ? (t + k * THREADS) : bj[r];
            bv[r] = pgt ? m2 : bv[r];
        }
    }
#pragma unroll
    for (int r = 0; r < R; r++) {
        float v2 = bv[r];
        int j2 = bj[r];
#pragma unroll
        for (int off = 32; off >= 1; off >>= 1) {
            const float ov = __shfl_down(v2, off, 64);
            const int   oj = __shfl_down(j2, off, 64);
            const bool take = (ov > v2) || (ov == v2 && oj < j2);
            v2 = take ? ov : v2;
            j2 = take ? oj : j2;
        }
        if (lane == 0) { redv[wid * R + r] = v2; redj[wid * R + r] = j2; }
    }
    __syncthreads();
    if (t < R) {
        float v2 = redv[t];
        int j2 = redj[t];
#pragma unroll
        for (int w = 1; w < NWAVE; w++) {
            const float ov = redv[w * R + t];
            const int   oj = redj[w * R + t];
            const bool take = (ov > v2) || (ov == v2 && oj < j2);
            v2 = take ? ov : v2;
            j2 = take ? oj : j2;
        }
        corr2[row0 + t] = (float)j2;
    }
}

extern "C" void kernel_launch(void* const* d_in, const int* in_sizes, int n_in,
                              void* d_out, int out_size, void* d_ws, size_t ws_size,
                              hipStream_t stream) {
    const float* x = (const float*)d_in[0];   // (2, 4096, 3) f32
    const float* y = (const float*)d_in[1];   // (2, 4096, 3) f32
    float* out = (float*)d_out;               // 1 + 8192 + 8192 floats
    float* ws = (float*)d_ws;

    float* u2 = ws + WS_U;
    float* v2 = ws + WS_V;
    float* err = ws + WS_ERR;
    float* xs0 = ws + WS_SOA + 0 * NROWS;
    float* xs1 = ws + WS_SOA + 1 * NROWS;
    float* xs2 = ws + WS_SOA + 2 * NROWS;
    float* xn  = ws + WS_SOA + 3 * NROWS;
    float* ys0 = ws + WS_SOA + 4 * NROWS;
    float* ys1 = ws + WS_SOA + 5 * NROWS;
    float* ys2 = ws + WS_SOA + 6 * NROWS;
    float* yn  = ws + WS_SOA + 7 * NROWS;

    prep_kernel<<<32, 512, 0, stream>>>(x, y, ws, out);

    dim3 grid(NBLK), blk(THREADS);
    // i=0 (even): u2 = f(v2==0), err0
    lse_single<1, 1><<<grid, blk, 0, stream>>>(xs0, xs1, xs2, xn, ys0, ys1, ys2, yn,
                                               v2, u2, &err[0], nullptr, nullptr);
    // i=1 (odd): v2 = g(u2); frozen iff err0<T
    lse_single<0, 0><<<grid, blk, 0, stream>>>(ys0, ys1, ys2, yn, xs0, xs1, xs2, xn,
                                               u2, v2, nullptr, &err[0], nullptr);
    // i=2 (even): u2 = f(v2), err1; frozen iff err0<T
    lse_single<1, 0><<<grid, blk, 0, stream>>>(xs0, xs1, xs2, xn, ys0, ys1, ys2, yn,
                                               v2, u2, &err[1], &err[0], nullptr);
    // i=3 (odd): v2 = g(u2); frozen iff err0<T | err1<T (err1 stays 0 if frozen)
    lse_single<0, 0><<<grid, blk, 0, stream>>>(ys0, ys1, ys2, yn, xs0, xs1, xs2, xn,
                                               u2, v2, nullptr, &err[0], &err[1]);
    // i=4 fused into row_final (u_final == f(v_final) in every freeze case).
    row_final<<<grid, blk, 0, stream>>>(xs0, xs1, xs2, xn, ys0, ys1, ys2, yn,
                                        v2, u2, out + 1, out);
    col_final<<<grid, blk, 0, stream>>>(ys0, ys1, ys2, yn, xs0, xs1, xs2, xn,
                                        u2, out + 1 + NROWS);
}